// Round 5
// baseline (261.600 us; speedup 1.0000x reference)
//
#include <hip/hip_runtime.h>

// Causal MHA forward, B=4 H=16 S=2048 D=64, fp32 I/O, bf16 MFMA compute.
// R5: two-kernel scheme.
//  1) qkv_prep: fp32 -> bf16 once (memory-bound): K as [bh][kv][d], V as
//     transposed [bh][d][kv], both with XOR chunk swizzle (chunk^=row&7)
//     baked into the GLOBAL layout so the main kernel's LDS tiles are
//     bank-conflict-free for b128 fragment reads.
//  2) mha_core: stages K/V tiles via global_load_lds dwordx4 (pure DMA, no
//     conversion VALU, no transpose writes).  BQ=64, 256-thread WGs
//     (4 waves x 16 q rows), anti-diagonal pairing -> uniform 33 tiles/WG,
//     grid 1024 = 4 WG/CU (4 barrier groups).  No-max softmax (R4), MFMA
//     denominator, raw v_exp_f32.
// Fallback: if ws_size < 33.6 MB, run the R4 single-kernel path.

typedef float  f32x4  __attribute__((ext_vector_type(4)));
typedef short  bf16x8 __attribute__((ext_vector_type(8)));

#define NH      16
#define DH      64
#define SEQ     2048
#define NSTATE  1024
#define ROW3    3072
#define NEG_BIG (-1e9f)
#define QSC     (0.125f * 1.4426950408889634f)   // 1/sqrt(64) * log2(e)
#define WS_NEED (33554432u)                       // K 16.78 MB + V^T 16.78 MB

// pack two fp32 -> two RNE bf16 in one u32
static __device__ __forceinline__ unsigned pk2(float x, float y) {
    unsigned ux = __builtin_bit_cast(unsigned, x);
    unsigned uy = __builtin_bit_cast(unsigned, y);
    ux += 0x7FFFu + ((ux >> 16) & 1u);
    uy += 0x7FFFu + ((uy >> 16) & 1u);
    return __builtin_amdgcn_perm(uy, ux, 0x07060302u);
}
static __device__ __forceinline__ short b1(float x) {
    unsigned u = __builtin_bit_cast(unsigned, x);
    u += 0x7FFFu + ((u >> 16) & 1u);
    return (short)(u >> 16);
}
static __device__ __forceinline__ void async16(const void* g, void* l) {
    __builtin_amdgcn_global_load_lds(
        (const __attribute__((address_space(1))) unsigned*)g,
        (__attribute__((address_space(3))) unsigned*)l, 16, 0, 0);
}

// ---------------- pre-pass: x fp32 -> Kbf / VTbf (swizzled bf16) ----------
__global__ __launch_bounds__(256)
void qkv_prep(const float* __restrict__ x, short* __restrict__ kbf,
              short* __restrict__ vt) {
    const int tid   = threadIdx.x;
    const int stile = blockIdx.x;      // 0..31 (64 s each)
    const int bh    = blockIdx.y;      // 0..63
    const int b = bh >> 4, h = bh & 15;
    const int s0 = stile * 64;

    const float* kg = x + (size_t)b * SEQ * ROW3 + NSTATE + h * DH;
    const float* vg = x + (size_t)b * SEQ * ROW3 + 2 * NSTATE + h * DH;

    __shared__ short T[64 * 66];       // V^T transpose buffer [d][s]

    // ---- K: convert + swizzled chunk write: slot c' = (d/8) ^ (kv&7) ----
    unsigned* kout = (unsigned*)kbf + ((size_t)bh * SEQ + s0) * 32;
#pragma unroll
    for (int j = 0; j < 4; ++j) {
        int idx = tid + 256 * j;
        int s   = idx >> 4;            // 0..63
        int dq  = (idx & 15) * 4;      // 0,4,...,60
        float4 v = *(const float4*)(kg + (size_t)(s0 + s) * ROW3 + dq);
        unsigned lo = pk2(v.x, v.y), hi = pk2(v.z, v.w);
        int cp = (dq >> 3) ^ (s & 7);
        unsigned* o = kout + s * 32 + cp * 4 + ((dq & 7) >> 1);
        o[0] = lo; o[1] = hi;
    }
    // ---- V: rows -> LDS transposed (stride 66: odd-dword, conflict-free) ----
#pragma unroll
    for (int j = 0; j < 4; ++j) {
        int idx = tid + 256 * j;
        int s   = idx >> 4;
        int dq  = (idx & 15) * 4;
        float4 v = *(const float4*)(vg + (size_t)(s0 + s) * ROW3 + dq);
        T[(dq + 0) * 66 + s] = b1(v.x);
        T[(dq + 1) * 66 + s] = b1(v.y);
        T[(dq + 2) * 66 + s] = b1(v.z);
        T[(dq + 3) * 66 + s] = b1(v.w);
    }
    __syncthreads();
    // ---- V^T out: rows d, swizzled chunks within this 64-kv segment ----
    {
        unsigned* vout = (unsigned*)vt + (size_t)bh * DH * (SEQ / 2) + (s0 >> 1);
        int d  = tid >> 2;             // 0..63
        int sc = (tid & 3) * 16;       // 0,16,32,48
        unsigned r[8];
#pragma unroll
        for (int k = 0; k < 8; ++k)
            r[k] = *(const unsigned*)&T[d * 66 + sc + k * 2];
        int c0  = sc >> 3;             // even chunk
        int c0p = c0 ^ (d & 7);
        int c1p = (c0 + 1) ^ (d & 7);
        uint4 w0 = {r[0], r[1], r[2], r[3]};
        uint4 w1 = {r[4], r[5], r[6], r[7]};
        *(uint4*)(vout + (size_t)d * (SEQ / 2) + c0p * 4) = w0;
        *(uint4*)(vout + (size_t)d * (SEQ / 2) + c1p * 4) = w1;
    }
}

// ---------------- main kernel: flash attention over bf16 K/V^T ------------
#define BQ2   64
#define NQB2  (SEQ / BQ2)     // 32 q-blocks, 16 pairs
#define PST   72

__global__ __launch_bounds__(256, 4)
void mha_core(const float* __restrict__ x, const short* __restrict__ kbf,
              const short* __restrict__ vt, float* __restrict__ out) {
    const int tid  = threadIdx.x;
    const int wave = tid >> 6;        // 0..3
    const int lane = tid & 63;
    const int l16  = lane & 15;
    const int quad = lane >> 4;
    const int sw   = l16 & 7;         // swizzle key

    const int pr = blockIdx.x;        // pair 0..15
    const int bh = blockIdx.y;
    const int b  = bh >> 4;
    const int h  = bh & 15;

    const float* xb = x + (size_t)b * SEQ * ROW3;
    float*       ob = out + (size_t)b * SEQ * NSTATE + h * DH;
    const char*  kgb = (const char*)kbf + (size_t)bh * SEQ * 128;     // [kv][128B]
    const char*  vgb = (const char*)vt + (size_t)bh * DH * SEQ * 2;   // [d][4096B]

    __shared__ __align__(16) short Klds[64 * 64];     // [kv][d-chunks swz] 8 KB
    __shared__ __align__(16) short Vlds[64 * 64];     // [d][kv-chunks swz] 8 KB
    __shared__ __align__(16) short Plds[4][16 * PST]; // per-wave P bounce

    bf16x8 vones;
#pragma unroll
    for (int i = 0; i < 8; ++i) vones[i] = (short)0x3F80;

#pragma unroll 1
    for (int ph = 0; ph < 2; ++ph) {
        const int qblk = ph ? (NQB2 - 1 - pr) : pr;   // pair (i,31-i): 33 tiles
        const int q0   = qblk * BQ2;
        const int qmin = q0 + wave * 16;
        const int qrow = qmin + l16;

        // ---- Q fragment (B-operand of S^T = K*Q^T), scaled by QSC ----
        bf16x8 qf[2];
        {
            const float* qp = xb + (size_t)qrow * ROW3 + h * DH + quad * 8;
#pragma unroll
            for (int f = 0; f < 2; ++f) {
                float4 a = *(const float4*)(qp + 32 * f);
                float4 c = *(const float4*)(qp + 32 * f + 4);
                union { bf16x8 v; unsigned u[4]; } qq;
                qq.u[0] = pk2(a.x * QSC, a.y * QSC);
                qq.u[1] = pk2(a.z * QSC, a.w * QSC);
                qq.u[2] = pk2(c.x * QSC, c.y * QSC);
                qq.u[3] = pk2(c.z * QSC, c.w * QSC);
                qf[f] = qq.v;
            }
        }

        f32x4 o[4];
#pragma unroll
        for (int t = 0; t < 4; ++t) o[t] = (f32x4){0.f, 0.f, 0.f, 0.f};
        f32x4 ol = (f32x4){0.f, 0.f, 0.f, 0.f};

        const int nt = q0 / 64 + 1;
#pragma unroll 1
        for (int it = 0; it < nt; ++it) {
            const int kv0 = it * 64;
            __syncthreads();   // protect K/V/P LDS reuse

            // ---- stage K and V^T tiles via async DMA (2+2 instr per wave) ----
            {
                const char* kt = kgb + (size_t)kv0 * 128;
                const char* vtt = vgb + (size_t)kv0 * 2;
#pragma unroll
                for (int j = 0; j < 2; ++j) {
                    int seg = wave * 2 + j;                 // 0..7
                    async16(kt + seg * 1024 + lane * 16,
                            (char*)Klds + seg * 1024);
                    int d = seg * 8 + (lane >> 3);
                    async16(vtt + (size_t)d * 4096 + (lane & 7) * 16,
                            (char*)Vlds + seg * 1024);
                }
            }
            __syncthreads();

            // ---- fragments: b128 reads, swizzle chunk = (quad+4f)^sw ----
            bf16x8 kf[4][2], vf[4][2];
#pragma unroll
            for (int t = 0; t < 4; ++t)
#pragma unroll
                for (int f = 0; f < 2; ++f) {
                    int off = (16 * t + l16) * 128 + (((quad + 4 * f) ^ sw) * 16);
                    kf[t][f] = *(const bf16x8*)((const char*)Klds + off);
                    vf[t][f] = *(const bf16x8*)((const char*)Vlds + off);
                }

            // ---- S^T = K*Q^T ----
            f32x4 sc[4];
#pragma unroll
            for (int t = 0; t < 4; ++t) {
                f32x4 c = (f32x4){0.f, 0.f, 0.f, 0.f};
                c = __builtin_amdgcn_mfma_f32_16x16x32_bf16(kf[t][0], qf[0], c, 0, 0, 0);
                c = __builtin_amdgcn_mfma_f32_16x16x32_bf16(kf[t][1], qf[1], c, 0, 0, 0);
                sc[t] = c;
            }
            if (it == nt - 1) {            // diagonal tile: causal mask
#pragma unroll
                for (int t = 0; t < 4; ++t)
#pragma unroll
                    for (int r = 0; r < 4; ++r) {
                        int kvg = kv0 + 16 * t + 4 * quad + r;
                        if (kvg > qrow) sc[t][r] = NEG_BIG;
                    }
            }

            // ---- no-max softmax numerator (raw v_exp_f32) ----
#pragma unroll
            for (int t = 0; t < 4; ++t)
#pragma unroll
                for (int r = 0; r < 4; ++r)
                    sc[t][r] = __builtin_amdgcn_exp2f(sc[t][r]);

            // ---- P bounce: C-layout -> A-operand via LDS ----
            short* pb = &Plds[wave][0];
#pragma unroll
            for (int t = 0; t < 4; ++t) {
                uint2 pk;
                pk.x = pk2(sc[t][0], sc[t][1]);
                pk.y = pk2(sc[t][2], sc[t][3]);
                *(uint2*)&pb[l16 * PST + 16 * t + 4 * quad] = pk;
            }
            __asm__ volatile("s_waitcnt lgkmcnt(0)" ::: "memory");
            bf16x8 pf0 = *(const bf16x8*)&pb[l16 * PST + quad * 8];
            bf16x8 pf1 = *(const bf16x8*)&pb[l16 * PST + quad * 8 + 32];

            // ---- O += P*V ; denom += P*ones ----
#pragma unroll
            for (int t = 0; t < 4; ++t) {
                f32x4 c = o[t];
                c = __builtin_amdgcn_mfma_f32_16x16x32_bf16(pf0, vf[t][0], c, 0, 0, 0);
                c = __builtin_amdgcn_mfma_f32_16x16x32_bf16(pf1, vf[t][1], c, 0, 0, 0);
                o[t] = c;
            }
            ol = __builtin_amdgcn_mfma_f32_16x16x32_bf16(pf0, vones, ol, 0, 0, 0);
            ol = __builtin_amdgcn_mfma_f32_16x16x32_bf16(pf1, vones, ol, 0, 0, 0);
        }

        // ---- epilogue ----
        {
            const int qtop = qmin + 4 * quad;
            float lr[4];
#pragma unroll
            for (int r = 0; r < 4; ++r) lr[r] = 1.0f / ol[r];
#pragma unroll
            for (int t = 0; t < 4; ++t)
#pragma unroll
                for (int r = 0; r < 4; ++r)
                    ob[(size_t)(qtop + r) * NSTATE + 16 * t + l16] = o[t][r] * lr[r];
        }
    }
}

// ---------------- R4 fallback (ws too small): single-kernel path ----------
#define BQ      128
#define BK      64
#define NQB     (SEQ / BQ)
#define KST     72
#define VST     72

__global__ __launch_bounds__(512, 4)
void mha_fwd_r4(const float* __restrict__ x, float* __restrict__ out) {
    const int tid  = threadIdx.x;
    const int wave = tid >> 6;
    const int lane = tid & 63;
    const int l16  = lane & 15;
    const int quad = lane >> 4;

    const int pr = blockIdx.x;
    const int bh = blockIdx.y;
    const int b  = bh >> 4;
    const int h  = bh & 15;

    const float* xb    = x + (size_t)b * SEQ * ROW3;
    const float* kbase = xb + NSTATE + h * DH;
    const float* vbase = xb + 2 * NSTATE + h * DH;
    float*       ob    = out + (size_t)b * SEQ * NSTATE + h * DH;

    __shared__ __align__(16) short Klds[BK * KST];
    __shared__ __align__(16) short Vlds[DH * VST];
    __shared__ __align__(16) short Plds[8][16 * PST];

    bf16x8 vones;
#pragma unroll
    for (int i = 0; i < 8; ++i) vones[i] = (short)0x3F80;

#pragma unroll 1
    for (int ph = 0; ph < 2; ++ph) {
        const int qblk = ph ? (NQB - 1 - pr) : pr;
        const int q0   = qblk * BQ;
        const int qmin = q0 + wave * 16;
        const int qrow = qmin + l16;

        bf16x8 qf[2];
        {
            const float* qp = xb + (size_t)qrow * ROW3 + h * DH + quad * 8;
#pragma unroll
            for (int f = 0; f < 2; ++f) {
                float4 a = *(const float4*)(qp + 32 * f);
                float4 c = *(const float4*)(qp + 32 * f + 4);
                union { bf16x8 v; unsigned u[4]; } qq;
                qq.u[0] = pk2(a.x * QSC, a.y * QSC);
                qq.u[1] = pk2(a.z * QSC, a.w * QSC);
                qq.u[2] = pk2(c.x * QSC, c.y * QSC);
                qq.u[3] = pk2(c.z * QSC, c.w * QSC);
                qf[f] = qq.v;
            }
        }

        f32x4 o[4];
#pragma unroll
        for (int t = 0; t < 4; ++t) o[t] = (f32x4){0.f, 0.f, 0.f, 0.f};
        f32x4 ol = (f32x4){0.f, 0.f, 0.f, 0.f};

        const int ntiles = q0 / BK + BQ / BK;
#pragma unroll 1
        for (int it = 0; it < ntiles; ++it) {
            const int kv0 = it * BK;
            __syncthreads();
#pragma unroll
            for (int i = 0; i < 2; ++i) {
                int p  = tid + 512 * i;
                int kv = p >> 4;
                int d  = (p & 15) * 4;
                const float* gp = kbase + (size_t)(kv0 + kv) * ROW3 + d;
                float4 v = *(const float4*)gp;
                uint2 pk;
                pk.x = pk2(v.x, v.y);
                pk.y = pk2(v.z, v.w);
                *(uint2*)&Klds[kv * KST + d] = pk;
            }
#pragma unroll
            for (int i = 0; i < 4; ++i) {
                int idx = tid + 512 * i;
                int d   = idx & 63;
                int kv  = (idx >> 6) * 2;
                const float* gp = vbase + (size_t)(kv0 + kv) * ROW3 + d;
                *(unsigned*)&Vlds[d * VST + kv] = pk2(gp[0], gp[ROW3]);
            }
            __syncthreads();

            if (kv0 > qmin + 15) continue;

            bf16x8 kf[4][2], vf[4][2];
#pragma unroll
            for (int t = 0; t < 4; ++t)
#pragma unroll
                for (int f = 0; f < 2; ++f) {
                    kf[t][f] = *(const bf16x8*)&Klds[(16 * t + l16) * KST + quad * 8 + 32 * f];
                    vf[t][f] = *(const bf16x8*)&Vlds[(16 * t + l16) * VST + quad * 8 + 32 * f];
                }

            f32x4 sc[4];
#pragma unroll
            for (int t = 0; t < 4; ++t) {
                f32x4 c = (f32x4){0.f, 0.f, 0.f, 0.f};
                c = __builtin_amdgcn_mfma_f32_16x16x32_bf16(kf[t][0], qf[0], c, 0, 0, 0);
                c = __builtin_amdgcn_mfma_f32_16x16x32_bf16(kf[t][1], qf[1], c, 0, 0, 0);
                sc[t] = c;
            }
            if (kv0 + BK - 1 > qmin) {
#pragma unroll
                for (int t = 0; t < 4; ++t)
#pragma unroll
                    for (int r = 0; r < 4; ++r) {
                        int kvg = kv0 + 16 * t + 4 * quad + r;
                        if (kvg > qrow) sc[t][r] = NEG_BIG;
                    }
            }
#pragma unroll
            for (int t = 0; t < 4; ++t)
#pragma unroll
                for (int r = 0; r < 4; ++r)
                    sc[t][r] = __builtin_amdgcn_exp2f(sc[t][r]);

            short* pb = &Plds[wave][0];
#pragma unroll
            for (int t = 0; t < 4; ++t) {
                uint2 pk;
                pk.x = pk2(sc[t][0], sc[t][1]);
                pk.y = pk2(sc[t][2], sc[t][3]);
                *(uint2*)&pb[l16 * PST + 16 * t + 4 * quad] = pk;
            }
            __asm__ volatile("s_waitcnt lgkmcnt(0)" ::: "memory");
            bf16x8 pf0 = *(const bf16x8*)&pb[l16 * PST + quad * 8];
            bf16x8 pf1 = *(const bf16x8*)&pb[l16 * PST + quad * 8 + 32];

#pragma unroll
            for (int t = 0; t < 4; ++t) {
                f32x4 c = o[t];
                c = __builtin_amdgcn_mfma_f32_16x16x32_bf16(pf0, vf[t][0], c, 0, 0, 0);
                c = __builtin_amdgcn_mfma_f32_16x16x32_bf16(pf1, vf[t][1], c, 0, 0, 0);
                o[t] = c;
            }
            ol = __builtin_amdgcn_mfma_f32_16x16x32_bf16(pf0, vones, ol, 0, 0, 0);
            ol = __builtin_amdgcn_mfma_f32_16x16x32_bf16(pf1, vones, ol, 0, 0, 0);
        }
        {
            const int qtop = qmin + 4 * quad;
            float lr[4];
#pragma unroll
            for (int r = 0; r < 4; ++r) lr[r] = 1.0f / ol[r];
#pragma unroll
            for (int t = 0; t < 4; ++t)
#pragma unroll
                for (int r = 0; r < 4; ++r)
                    ob[(size_t)(qtop + r) * NSTATE + 16 * t + l16] = o[t][r] * lr[r];
        }
    }
}

extern "C" void kernel_launch(void* const* d_in, const int* in_sizes, int n_in,
                              void* d_out, int out_size, void* d_ws, size_t ws_size,
                              hipStream_t stream) {
    const float* x = (const float*)d_in[0];   // [B,S,3*NSTATE] fp32
    float* out = (float*)d_out;               // [B,S,NSTATE] fp32
    if (ws_size >= WS_NEED) {
        short* kbf = (short*)d_ws;
        short* vt  = (short*)((char*)d_ws + WS_NEED / 2);
        hipLaunchKernelGGL(qkv_prep, dim3(SEQ / 64, 4 * NH), dim3(256), 0, stream,
                           x, kbf, vt);
        hipLaunchKernelGGL(mha_core, dim3(NQB2 / 2, 4 * NH), dim3(256), 0, stream,
                           x, kbf, vt, out);
    } else {
        hipLaunchKernelGGL(mha_fwd_r4, dim3(NQB / 2, 4 * NH), dim3(512), 0, stream,
                           x, out);
    }
}